// Round 4
// baseline (442.810 us; speedup 1.0000x reference)
//
#include <hip/hip_runtime.h>

typedef unsigned short u16;
typedef __bf16 bf16x8 __attribute__((ext_vector_type(8)));
typedef float  f32x4  __attribute__((ext_vector_type(4)));

#define EPSF 1e-6f

__device__ __forceinline__ u16 f2b(float f) {
  unsigned u = __float_as_uint(f);
  u += 0x7fffu + ((u >> 16) & 1u);          // round-nearest-even
  return (u16)(u >> 16);
}
__device__ __forceinline__ float b2f(u16 u) { return __uint_as_float(((unsigned)u) << 16); }
// Native HW conversion (RNE, same bits as f2b) — lets the compiler emit v_cvt_*_bf16.
__device__ __forceinline__ u16 f2bh(float f) { return __builtin_bit_cast(u16, (__bf16)f); }

// Async global->LDS DMA, 16 B/lane. LDS dest = wave-uniform base + lane*16.
__device__ __forceinline__ void dma16(const u16* g, u16* l) {
  __builtin_amdgcn_global_load_lds(
      (const __attribute__((address_space(1))) unsigned int*)g,
      (__attribute__((address_space(3))) unsigned int*)l, 16, 0, 0);
}

// ---------------------------------------------------------------------------
// One-shot f32 -> bf16 conversion of hidden + all weights.
// ---------------------------------------------------------------------------
__global__ void dsv4_cvt(const float* __restrict__ hidden, const float* __restrict__ wq_a,
                         const float* __restrict__ wq_b, const float* __restrict__ wkv,
                         const float* __restrict__ wo_a, const float* __restrict__ wo_b,
                         u16* hb, u16* qab, u16* qbb, u16* kvb, u16* oab, u16* obb)
{
  long c = (long)blockIdx.x * 256 + threadIdx.x;
  const float* s; u16* d; long off;
  if      (c < 1048576) { s = hidden; d = hb;  off = c; }
  else if (c < 1835008) { s = wq_a;   d = qab; off = c - 1048576; }
  else if (c < 2621440) { s = wq_b;   d = qbb; off = c - 1835008; }
  else if (c < 2686976) { s = wkv;    d = kvb; off = c - 2621440; }
  else if (c < 2949120) { s = wo_a;   d = oab; off = c - 2686976; }
  else                  { s = wo_b;   d = obb; off = c - 2949120; }
  const float* p = s + off * 8;
  float4 f0 = *(const float4*)p;
  float4 f1 = *(const float4*)(p + 4);
  union { u16 h[8]; int4 v; } u;
  u.h[0] = f2b(f0.x); u.h[1] = f2b(f0.y); u.h[2] = f2b(f0.z); u.h[3] = f2b(f0.w);
  u.h[4] = f2b(f1.x); u.h[5] = f2b(f1.y); u.h[6] = f2b(f1.z); u.h[7] = f2b(f1.w);
  *(int4*)(d + off * 8) = u.v;
}

// ---------------------------------------------------------------------------
// GEMM: C[M,N] = A[M,K] @ B[N,K]^T, all-bf16, global_load_lds staging,
// XOR-swizzled LDS. NEW (T4): 4 LDS buffers, prefetch depth 3, COUNTED vmcnt:
//   step t: vmcnt(2P) [t's P loads retired, issued 3 phases ago] ; s_barrier
//           [all waves certified -> whole tile t visible; also certifies
//            everyone finished reading buf[(t-1)&3]] ; issue t+3 into that
//           buffer ; ds_read buf[t&3] ; MFMA.
//   Tail: vmcnt steps down 2P -> P -> 0 (vmcnt retires oldest-first).
// ---------------------------------------------------------------------------
template<int BM, bool C_F32>
__global__ __launch_bounds__(256, 2)
void dsv4_gemm(const u16* __restrict__ A, int lda, long sAz,
               const u16* __restrict__ B, int ldb, long sBz,
               void* __restrict__ Cv, int ldc, long sCz,
               int K, int splitTile,
               const u16* __restrict__ Baux, void* __restrict__ Caux, int ldcAux)
{
  constexpr int AI = (BM * 4) / 256;        // A-DMAs per step (1 or 2)
  constexpr int NJ = (BM == 128) ? 4 : 2;
  __shared__ __align__(16) u16 As[4 * BM * 32];
  __shared__ __align__(16) u16 Bs[4 * 128 * 32];

  const int tid   = threadIdx.x;
  const int lane  = tid & 63;
  const int q     = lane >> 4;
  const int l16   = lane & 15;
  const int wid   = tid >> 6;
  const int wbase = tid & 192;

  int n0 = blockIdx.x * 128;
  const int m0 = blockIdx.y * BM;
  void* Cp = Cv;
  if ((int)blockIdx.x >= splitTile) {
    B = Baux; Cp = Caux; ldc = ldcAux;
    n0 = ((int)blockIdx.x - splitTile) * 128;
  }
  A += (long)blockIdx.z * sAz;
  B += (long)blockIdx.z * sBz;

  const u16* gA[AI]; u16* lA[AI];
#pragma unroll
  for (int j = 0; j < AI; j++) {
    int L = j * 256 + tid, row = L >> 2, c = (L & 3) ^ ((row >> 1) & 3);
    gA[j] = A + (long)(m0 + row) * lda + c * 8;
    lA[j] = As + (j * 256 + wbase) * 8;
  }
  const u16* gB[2]; u16* lB[2];
#pragma unroll
  for (int j = 0; j < 2; j++) {
    int L = j * 256 + tid, row = L >> 2, c = (L & 3) ^ ((row >> 1) & 3);
    gB[j] = B + (long)(n0 + row) * ldb + c * 8;
    lB[j] = Bs + (j * 256 + wbase) * 8;
  }

  f32x4 acc[4][NJ];
#pragma unroll
  for (int i = 0; i < 4; i++)
#pragma unroll
    for (int j = 0; j < NJ; j++) { f32x4 z = {0.f, 0.f, 0.f, 0.f}; acc[i][j] = z; }

  const int wm = (BM == 128) ? (wid >> 1) * 64 : 0;
  const int wn = (BM == 128) ? (wid & 1) * 64 : wid * 32;

  auto issue = [&](int s) {
    const int k  = s << 5;
    const int bi = s & 3;
    const int na = bi * (BM * 32);
    const int nb = bi * (128 * 32);
#pragma unroll
    for (int j = 0; j < AI; j++) dma16(gA[j] + k, lA[j] + na);
#pragma unroll
    for (int j = 0; j < 2; j++)  dma16(gB[j] + k, lB[j] + nb);
  };

  const int nsteps = K >> 5;                 // always >= 32 here
  issue(0); issue(1); issue(2);

  for (int t = 0; t < nsteps; t++) {
    if (t + 2 < nsteps) {                    // 2 steps still in flight
      if constexpr (BM == 128) asm volatile("s_waitcnt vmcnt(8)" ::: "memory");
      else                     asm volatile("s_waitcnt vmcnt(6)" ::: "memory");
    } else if (t + 1 < nsteps) {             // 1 step in flight
      if constexpr (BM == 128) asm volatile("s_waitcnt vmcnt(4)" ::: "memory");
      else                     asm volatile("s_waitcnt vmcnt(3)" ::: "memory");
    } else {
      asm volatile("s_waitcnt vmcnt(0)" ::: "memory");
    }
    __builtin_amdgcn_s_barrier();            // all waves certified tile t

    if (t + 3 < nsteps) issue(t + 3);        // overwrites buf[(t-1)&3] (safe)

    const int aoff = (t & 3) * (BM * 32);
    const int boff = (t & 3) * (128 * 32);

    bf16x8 af[4], bg[NJ];
#pragma unroll
    for (int i = 0; i < 4; i++) {
      int row = wm + i * 16 + l16;
      af[i] = *(const bf16x8*)&As[aoff + row * 32 + ((q ^ ((row >> 1) & 3)) << 3)];
    }
#pragma unroll
    for (int j = 0; j < NJ; j++) {
      int row = wn + j * 16 + l16;
      bg[j] = *(const bf16x8*)&Bs[boff + row * 32 + ((q ^ ((row >> 1) & 3)) << 3)];
    }
#pragma unroll
    for (int i = 0; i < 4; i++)
#pragma unroll
      for (int j = 0; j < NJ; j++)
        acc[i][j] = __builtin_amdgcn_mfma_f32_16x16x32_bf16(af[i], bg[j], acc[i][j], 0, 0, 0);
  }

#pragma unroll
  for (int i = 0; i < 4; i++)
#pragma unroll
    for (int j = 0; j < NJ; j++)
#pragma unroll
      for (int rr = 0; rr < 4; rr++) {
        long row = m0 + wm + i * 16 + q * 4 + rr;
        int  col = n0 + wn + j * 16 + l16;
        if (C_F32)
          ((float*)Cp)[row * ldc + col + (long)blockIdx.z * sCz] = acc[i][j][rr];
        else
          ((u16*)Cp)[row * ldc + col + (long)blockIdx.z * sCz] = f2b(acc[i][j][rr]);
      }
}

// ---------------------------------------------------------------------------
// RMSNorm over rows of width W (one block / row). X,Y internal bf16; g f32.
// ---------------------------------------------------------------------------
__global__ void dsv4_rmsnorm(const u16* __restrict__ X, const float* __restrict__ g,
                             u16* __restrict__ Y, int W, float invW)
{
  __shared__ float wsum[4];
  const int row = blockIdx.x;
  const u16* x = X + (long)row * W;
  u16* y = Y + (long)row * W;
  float ss = 0.f;
  for (int i = threadIdx.x; i < W; i += 256) { float v = b2f(x[i]); ss += v * v; }
#pragma unroll
  for (int o = 32; o > 0; o >>= 1) ss += __shfl_xor(ss, o);
  const int wid = threadIdx.x >> 6;
  if ((threadIdx.x & 63) == 0) wsum[wid] = ss;
  __syncthreads();
  float tot = wsum[0] + wsum[1] + wsum[2] + wsum[3];
  float scale = rsqrtf(tot * invW + EPSF);
  for (int i = threadIdx.x; i < W; i += 256)
    y[i] = f2b(b2f(x[i]) * scale * g[i]);
}

// ---------------------------------------------------------------------------
// kv finalize: RMSNorm(128) + write V^T (128 x 2048) and RoPE'd K (2048 x 128).
// ---------------------------------------------------------------------------
__global__ void dsv4_kv_finalize(const u16* __restrict__ KVp, const float* __restrict__ g,
                                 u16* __restrict__ Kout, u16* __restrict__ VTout)
{
  const int wid  = threadIdx.x >> 6;
  const int lane = threadIdx.x & 63;
  const int row  = blockIdx.x * 4 + wid;
  const u16* x = KVp + (long)row * 128;
  float x0 = b2f(x[2 * lane]);
  float x1 = b2f(x[2 * lane + 1]);
  float ss = x0 * x0 + x1 * x1;
#pragma unroll
  for (int o = 32; o > 0; o >>= 1) ss += __shfl_xor(ss, o);
  float scale = rsqrtf(ss * (1.f / 128.f) + EPSF);
  float v0 = x0 * scale * g[2 * lane];
  float v1 = x1 * scale * g[2 * lane + 1];
  VTout[(long)(2 * lane) * 2048 + row]     = f2b(v0);
  VTout[(long)(2 * lane + 1) * 2048 + row] = f2b(v1);
  float k0 = v0, k1 = v1;
  if (lane >= 32) {
    int i = lane - 32;
    float invf = powf(10000.f, -(float)i * (1.f / 32.f));
    float sn, cc;
    sincosf((float)row * invf, &sn, &cc);               // sin FIRST, cos second
    k0 = v0 * cc - v1 * sn;
    k1 = v0 * sn + v1 * cc;
  }
  Kout[(long)row * 128 + 2 * lane]     = f2b(k0);
  Kout[(long)row * 128 + 2 * lane + 1] = f2b(k1);
}

// ---------------------------------------------------------------------------
// Flash attention v3 + VALU diet (unchanged — verified 99.7-100.8us):
//  - Defer-max (T13), lazy row-sum, one-FMA softmax scale, HW bf16 cvts,
//    s_setprio around MFMA clusters.
// ---------------------------------------------------------------------------
__device__ __forceinline__ void attn_step(
    const bf16x8* qf, bool diag, const u16* __restrict__ KsB,
    const u16* __restrict__ VsB, u16* __restrict__ PsW,
    int w, int qd, int l16, int swz, float* m, float* negm, float* l, f32x4* o)
{
  const float scl2 = 0.12754245006257017f;     // (1/sqrt(128)) * log2(e)
  const float THRU = 62.0f;                    // defer-max threshold ~ 8/scl2
  f32x4 st[4];
#pragma unroll
  for (int i = 0; i < 4; i++) { f32x4 z = {0.f, 0.f, 0.f, 0.f}; st[i] = z; }

  __builtin_amdgcn_s_setprio(1);
#pragma unroll
  for (int ks = 0; ks < 4; ks++) {             // S = Q K^T (16 x 64 per wave)
#pragma unroll
    for (int nt = 0; nt < 4; nt++) {
      int row = nt * 16 + l16;
      bf16x8 bk = *(const bf16x8*)&KsB[row * 128 + ((((ks << 2) + qd) ^ swz) << 3)];
      st[nt] = __builtin_amdgcn_mfma_f32_16x16x32_bf16(qf[ks], bk, st[nt], 0, 0, 0);
    }
  }
  __builtin_amdgcn_s_setprio(0);

  if (diag) {                                  // causal mask (raw-score domain)
#pragma unroll
    for (int nt = 0; nt < 4; nt++)
#pragma unroll
      for (int rr = 0; rr < 4; rr++)
        if ((nt * 16 + l16) > (w * 16 + qd * 4 + rr)) st[nt][rr] = -3.0e38f;
  }

  float tm[4];
  bool need = false;
#pragma unroll
  for (int rr = 0; rr < 4; rr++) {             // row max across quad's 16 lanes
    float t = fmaxf(fmaxf(st[0][rr], st[1][rr]), fmaxf(st[2][rr], st[3][rr]));
    t = fmaxf(t, __shfl_xor(t, 1));
    t = fmaxf(t, __shfl_xor(t, 2));
    t = fmaxf(t, __shfl_xor(t, 4));
    t = fmaxf(t, __shfl_xor(t, 8));
    tm[rr] = t;
    need = need || (t > m[rr] + THRU);
  }
  if (__any(need)) {                           // rare: rescale running state
#pragma unroll
    for (int rr = 0; rr < 4; rr++) {
      float mn = fmaxf(m[rr], tm[rr]);
      float a  = exp2f(scl2 * (m[rr] - mn));
      m[rr] = mn; negm[rr] = -scl2 * mn;
      l[rr] *= a;
#pragma unroll
      for (int nt = 0; nt < 8; nt++) o[nt][rr] *= a;
    }
  }

#pragma unroll
  for (int nt = 0; nt < 4; nt++)               // P + partial l + LDS (swizzled)
#pragma unroll
    for (int rr = 0; rr < 4; rr++) {
      float p = exp2f(fmaf(st[nt][rr], scl2, negm[rr]));
      l[rr] += p;
      int row = qd * 4 + rr;
      int cl2 = ((nt << 1) + (l16 >> 3)) ^ (row & 7);
      PsW[row * 64 + (cl2 << 3) + (l16 & 7)] = f2bh(p);
    }
  asm volatile("s_waitcnt lgkmcnt(0)" ::: "memory");

  __builtin_amdgcn_s_setprio(1);
#pragma unroll
  for (int ks = 0; ks < 2; ks++) {             // O += P V (16 x 128 per wave)
    bf16x8 ap = *(const bf16x8*)&PsW[l16 * 64 + ((((ks << 2) + qd) ^ swz) << 3)];
#pragma unroll
    for (int nt = 0; nt < 8; nt++) {
      int row = nt * 16 + l16;
      bf16x8 bv = *(const bf16x8*)&VsB[row * 64 + ((((ks << 2) + qd) ^ swz) << 3)];
      o[nt] = __builtin_amdgcn_mfma_f32_16x16x32_bf16(ap, bv, o[nt], 0, 0, 0);
    }
  }
  __builtin_amdgcn_s_setprio(0);
}

__global__ __launch_bounds__(256, 2)
void dsv4_attn(const u16* __restrict__ Q, const u16* __restrict__ Km,
               const u16* __restrict__ VT, const float* __restrict__ sinkp,
               u16* __restrict__ O)
{
  __shared__ __align__(16) u16 Ks[2][64 * 128];
  __shared__ __align__(16) u16 Vs[2][128 * 64];
  __shared__ __align__(16) u16 Ps[4][16 * 64];

  const int b  = blockIdx.x;                   // 0..15
  const int h  = blockIdx.y;
  const int qtA = 31 - b, qtB = b;
  const int n1 = qtA + 1, nT = n1 + qtB + 1;   // nT == 33 for all blocks
  const int tid  = threadIdx.x;
  const int lane = tid & 63;
  const int w    = tid >> 6;
  const int qd   = lane >> 4;
  const int l16  = lane & 15;
  const int swz  = l16 & 7;

  // ---- Q fragments for BOTH tiles in registers, RoPE fused ----
  bf16x8 qfA[4], qfB[4];
#pragma unroll
  for (int t = 0; t < 2; t++) {
    int srow = (t ? qtB : qtA) * 64 + w * 16 + l16;
    const u16* qp = Q + (long)srow * 4096 + h * 128 + qd * 8;
    bf16x8* qf = t ? qfB : qfA;
#pragma unroll
    for (int ks = 0; ks < 4; ks++) {
      union { int4 v; u16 hh[8]; } u;
      u.v = *(const int4*)(qp + ks * 32);
      if (ks >= 2) {                           // dh >= 64: rope pairs (in-lane)
#pragma unroll
        for (int j = 0; j < 4; j++) {
          int i = (ks - 2) * 16 + qd * 4 + j;
          float invf = exp2f((float)i * (-13.287712379549449f / 32.f));
          float sn, cc;
          sincosf((float)srow * invf, &sn, &cc);   // sin FIRST, cos second
          float x0 = b2f(u.hh[2 * j]), x1 = b2f(u.hh[2 * j + 1]);
          u.hh[2 * j]     = f2b(x0 * cc - x1 * sn);
          u.hh[2 * j + 1] = f2b(x0 * sn + x1 * cc);
        }
      }
      qf[ks] = *(bf16x8*)&u;
    }
  }

  // ---- K/V DMA source pointers (XOR-swizzled chunk) + LDS offsets ----
  const u16* gK[4]; const u16* gV[4]; int lKo[4], lVo[4];
#pragma unroll
  for (int j = 0; j < 4; j++) {
    int cl = j * 256 + tid;
    int krow = cl >> 4, kc = (cl & 15) ^ (krow & 7);
    gK[j] = Km + (long)krow * 128 + kc * 8;
    lKo[j] = (j * 256 + (tid & 192)) * 8;
    int vrow = cl >> 3, vc = (cl & 7) ^ (vrow & 7);
    gV[j] = VT + (long)vrow * 2048 + vc * 8;
    lVo[j] = (j * 256 + (tid & 192)) * 8;
  }

  float m[4], negm[4], l[4];
  f32x4 o[8];
#pragma unroll
  for (int i = 0; i < 4; i++) { m[i] = -INFINITY; negm[i] = 0.f; l[i] = 0.f; }
#pragma unroll
  for (int i = 0; i < 8; i++) { f32x4 z = {0.f, 0.f, 0.f, 0.f}; o[i] = z; }

  const float sink2 = sinkp[h] * 1.4426950408889634f;   // log2 domain

  // Preload kt=0 into buffer 0.
#pragma unroll
  for (int j = 0; j < 4; j++) { dma16(gK[j], &Ks[0][lKo[j]]); dma16(gV[j], &Vs[0][lVo[j]]); }

  for (int it = 0; it < nT; ++it) {
    int nxt = it + 1;
    if (nxt < nT) {                            // prefetch next tile's K/V
      int kt2 = (nxt < n1) ? nxt : nxt - n1;
      int pb = nxt & 1;
#pragma unroll
      for (int j = 0; j < 4; j++) {
        dma16(gK[j] + (long)kt2 * 8192, &Ks[pb][lKo[j]]);
        dma16(gV[j] + (long)kt2 * 64,   &Vs[pb][lVo[j]]);
      }
    }
    asm volatile("s_waitcnt vmcnt(8)" ::: "memory");  // current buffer landed
    asm volatile("s_barrier" ::: "memory");           // publish (no full drain)
    const int cb = it & 1;

    if (it < n1)
      attn_step(qfA, it == n1 - 1, Ks[cb], Vs[cb], Ps[w], w, qd, l16, swz, m, negm, l, o);
    else
      attn_step(qfB, it == nT - 1, Ks[cb], Vs[cb], Ps[w], w, qd, l16, swz, m, negm, l, o);

    asm volatile("s_barrier" ::: "memory");           // reads done before overwrite

    if (it == n1 - 1) {                        // finalize tile A, reset state
      float inv[4];
#pragma unroll
      for (int rr = 0; rr < 4; rr++) {
        float ls = l[rr];
        ls += __shfl_xor(ls, 1);
        ls += __shfl_xor(ls, 2);
        ls += __shfl_xor(ls, 4);
        ls += __shfl_xor(ls, 8);
        inv[rr] = 1.f / (ls + exp2f(sink2 + negm[rr]));
      }
#pragma unroll
      for (int nt = 0; nt < 8; nt++)
#pragma unroll
        for (int rr = 0; rr < 4; rr++)
          O[(long)(qtA * 64 + w * 16 + qd * 4 + rr) * 4096 + h * 128 + nt * 16 + l16] =
              f2bh(o[nt][rr] * inv[rr]);
#pragma unroll
      for (int i = 0; i < 4; i++) { m[i] = -INFINITY; negm[i] = 0.f; l[i] = 0.f; }
#pragma unroll
      for (int i = 0; i < 8; i++) { f32x4 z = {0.f, 0.f, 0.f, 0.f}; o[i] = z; }
    }
  }

  float inv[4];
#pragma unroll
  for (int rr = 0; rr < 4; rr++) {
    float ls = l[rr];
    ls += __shfl_xor(ls, 1);
    ls += __shfl_xor(ls, 2);
    ls += __shfl_xor(ls, 4);
    ls += __shfl_xor(ls, 8);
    inv[rr] = 1.f / (ls + exp2f(sink2 + negm[rr]));
  }
#pragma unroll
  for (int nt = 0; nt < 8; nt++)
#pragma unroll
    for (int rr = 0; rr < 4; rr++)
      O[(long)(qtB * 64 + w * 16 + qd * 4 + rr) * 4096 + h * 128 + nt * 16 + l16] =
          f2bh(o[nt][rr] * inv[rr]);
}

// ---------------------------------------------------------------------------
extern "C" void kernel_launch(void* const* d_in, const int* in_sizes, int n_in,
                              void* d_out, int out_size, void* d_ws, size_t ws_size,
                              hipStream_t stream)
{
  (void)in_sizes; (void)n_in; (void)out_size; (void)ws_size;
  const float* hidden = (const float*)d_in[0];
  const float* wq_a  = (const float*)d_in[2];
  const float* q_g   = (const float*)d_in[3];
  const float* wq_b  = (const float*)d_in[4];
  const float* wkv   = (const float*)d_in[5];
  const float* kv_g  = (const float*)d_in[6];
  const float* wo_a  = (const float*)d_in[7];
  const float* wo_b  = (const float*)d_in[8];
  const float* sinkp = (const float*)d_in[9];
  float* out = (float*)d_out;

  char* ws = (char*)d_ws;
  u16* hb     = (u16*)(ws);
  u16* low    = (u16*)(ws);
  u16* qab    = (u16*)(ws + (17ul << 20));
  u16* qr     = (u16*)(ws + (17ul << 20));
  u16* qbb    = (u16*)(ws + (30ul << 20));
  u16* kvb    = (u16*)(ws + (43ul << 20));
  u16* oab    = (u16*)(ws + (45ul << 20));
  u16* obb    = (u16*)(ws + (50ul << 20));
  u16* qbuf   = (u16*)(ws + (67ul << 20));
  u16* attnout= (u16*)(ws + (84ul << 20));
  u16* qr_pre = (u16*)(ws + (101ul << 20));
  u16* kvpre  = (u16*)(ws + (108ul << 20));
  u16* kmat   = (u16*)(ws + (108ul << 20) + 524288u);
  u16* vt     = (u16*)(ws + (108ul << 20) + 1048576u);

  const int BIG = 1 << 29;
  dim3 blk(256);

  dsv4_cvt<<<15616, blk, 0, stream>>>(hidden, wq_a, wq_b, wkv, wo_a, wo_b,
                                      hb, qab, qbb, kvb, oab, obb);
  // G1 (+fused wkv as col-tile 12): qr_pre = hidden@wq_a^T, kvpre = hidden@wkv^T
  dsv4_gemm<64, false><<<dim3(13, 32, 1), blk, 0, stream>>>(
      hb, 4096, 0, qab, 4096, 0, qr_pre, 1536, 0, 4096, 12, kvb, kvpre, 128);
  dsv4_rmsnorm<<<2048, blk, 0, stream>>>(qr_pre, q_g, qr, 1536, 1.f / 1536.f);
  dsv4_kv_finalize<<<512, blk, 0, stream>>>(kvpre, kv_g, kmat, vt);
  // G2: qbuf = qr @ wq_b^T  (un-roped; attn ropes Q in-register)
  dsv4_gemm<128, false><<<dim3(32, 16, 1), blk, 0, stream>>>(
      qr, 1536, 0, qbb, 1536, 0, qbuf, 4096, 0, 1536, BIG, nullptr, nullptr, 0);
  dsv4_attn<<<dim3(16, 32, 1), blk, 0, stream>>>(qbuf, kmat, vt, sinkp, attnout);
  // G4: grouped low[:, g*512:+512] = attnout[:, g*1024:+1024] @ wo_a[g]^T
  dsv4_gemm<64, false><<<dim3(4, 32, 4), blk, 0, stream>>>(
      attnout, 4096, 1024, oab, 1024, 524288, low, 2048, 512, 1024, BIG,
      nullptr, nullptr, 0);
  // G5: out = low @ wo_b^T (f32 store)
  dsv4_gemm<128, true><<<dim3(32, 16, 1), blk, 0, stream>>>(
      low, 2048, 0, obb, 2048, 0, out, 4096, 0, 2048, BIG, nullptr, nullptr, 0);
}

// Round 5
// 403.066 us; speedup vs baseline: 1.0986x; 1.0986x over previous
//
#include <hip/hip_runtime.h>

typedef unsigned short u16;
typedef __bf16 bf16x8 __attribute__((ext_vector_type(8)));
typedef float  f32x4  __attribute__((ext_vector_type(4)));

#define EPSF 1e-6f

__device__ __forceinline__ u16 f2b(float f) {
  unsigned u = __float_as_uint(f);
  u += 0x7fffu + ((u >> 16) & 1u);          // round-nearest-even
  return (u16)(u >> 16);
}
__device__ __forceinline__ float b2f(u16 u) { return __uint_as_float(((unsigned)u) << 16); }
// Native HW conversion (RNE, same bits as f2b) — lets the compiler emit v_cvt_*_bf16.
__device__ __forceinline__ u16 f2bh(float f) { return __builtin_bit_cast(u16, (__bf16)f); }

// Async global->LDS DMA, 16 B/lane. LDS dest = wave-uniform base + lane*16.
__device__ __forceinline__ void dma16(const u16* g, u16* l) {
  __builtin_amdgcn_global_load_lds(
      (const __attribute__((address_space(1))) unsigned int*)g,
      (__attribute__((address_space(3))) unsigned int*)l, 16, 0, 0);
}

// ---------------------------------------------------------------------------
// One-shot f32 -> bf16 conversion of hidden + all weights.
// ---------------------------------------------------------------------------
__global__ void dsv4_cvt(const float* __restrict__ hidden, const float* __restrict__ wq_a,
                         const float* __restrict__ wq_b, const float* __restrict__ wkv,
                         const float* __restrict__ wo_a, const float* __restrict__ wo_b,
                         u16* hb, u16* qab, u16* qbb, u16* kvb, u16* oab, u16* obb)
{
  long c = (long)blockIdx.x * 256 + threadIdx.x;
  const float* s; u16* d; long off;
  if      (c < 1048576) { s = hidden; d = hb;  off = c; }
  else if (c < 1835008) { s = wq_a;   d = qab; off = c - 1048576; }
  else if (c < 2621440) { s = wq_b;   d = qbb; off = c - 1835008; }
  else if (c < 2686976) { s = wkv;    d = kvb; off = c - 2621440; }
  else if (c < 2949120) { s = wo_a;   d = oab; off = c - 2686976; }
  else                  { s = wo_b;   d = obb; off = c - 2949120; }
  const float* p = s + off * 8;
  float4 f0 = *(const float4*)p;
  float4 f1 = *(const float4*)(p + 4);
  union { u16 h[8]; int4 v; } u;
  u.h[0] = f2b(f0.x); u.h[1] = f2b(f0.y); u.h[2] = f2b(f0.z); u.h[3] = f2b(f0.w);
  u.h[4] = f2b(f1.x); u.h[5] = f2b(f1.y); u.h[6] = f2b(f1.z); u.h[7] = f2b(f1.w);
  *(int4*)(d + off * 8) = u.v;
}

// ---------------------------------------------------------------------------
// GEMM: C[M,N] = A[M,K] @ B[N,K]^T, all-bf16, global_load_lds staging.
// NEW: BK=64 K-tiles, ONE barrier per tile (was 2 per 64-K), 2x MFMA per
// barrier, double-buffered LDS, issue-early/wait-late, setprio on MFMA
// clusters. 8-chunk XOR swizzle: write chunk (L&7)^(row&7) from global,
// read chunk ((ks2*4+qd)^(l16&7)) — row&7==l16&7 on read rows, so the
// involution matches and ds_read_b128 is 2-way max (conflict-free).
// ---------------------------------------------------------------------------
template<int BM, bool C_F32>
__global__ __launch_bounds__(256, 2)
void dsv4_gemm(const u16* __restrict__ A, int lda, long sAz,
               const u16* __restrict__ B, int ldb, long sBz,
               void* __restrict__ Cv, int ldc, long sCz,
               int K, int splitTile,
               const u16* __restrict__ Baux, void* __restrict__ Caux, int ldcAux)
{
  constexpr int AJ = BM / 32;               // A dma16/thread/tile: 128->4, 64->2
  constexpr int NJ = (BM == 128) ? 4 : 2;
  __shared__ __align__(16) u16 As[2 * BM * 64];
  __shared__ __align__(16) u16 Bs[2 * 128 * 64];

  const int tid   = threadIdx.x;
  const int lane  = tid & 63;
  const int qd    = lane >> 4;
  const int l16   = lane & 15;
  const int wid   = tid >> 6;
  const int wbase = tid & 192;
  const int swz   = l16 & 7;

  int n0 = blockIdx.x * 128;
  const int m0 = blockIdx.y * BM;
  void* Cp = Cv;
  if ((int)blockIdx.x >= splitTile) {
    B = Baux; Cp = Caux; ldc = ldcAux;
    n0 = ((int)blockIdx.x - splitTile) * 128;
  }
  A += (long)blockIdx.z * sAz;
  B += (long)blockIdx.z * sBz;

  // Staging pointers: tile rows have 8 chunks of 8 u16 (16B); 8 threads/row.
  const u16* gA[AJ]; u16* lA[AJ];
#pragma unroll
  for (int j = 0; j < AJ; j++) {
    int L = j * 256 + tid, row = L >> 3, c = (L & 7) ^ (row & 7);
    gA[j] = A + (long)(m0 + row) * lda + c * 8;
    lA[j] = As + (j * 256 + wbase) * 8;
  }
  const u16* gB[4]; u16* lB[4];
#pragma unroll
  for (int j = 0; j < 4; j++) {
    int L = j * 256 + tid, row = L >> 3, c = (L & 7) ^ (row & 7);
    gB[j] = B + (long)(n0 + row) * ldb + c * 8;
    lB[j] = Bs + (j * 256 + wbase) * 8;
  }

  f32x4 acc[4][NJ];
#pragma unroll
  for (int i = 0; i < 4; i++)
#pragma unroll
    for (int j = 0; j < NJ; j++) { f32x4 z = {0.f, 0.f, 0.f, 0.f}; acc[i][j] = z; }

  const int wm = (BM == 128) ? (wid >> 1) * 64 : 0;
  const int wn = (BM == 128) ? (wid & 1) * 64 : wid * 32;

  auto issue = [&](int s) {
    const int k  = s << 6;
    const int ab = (s & 1) * (BM * 64);
    const int bb = (s & 1) * (128 * 64);
#pragma unroll
    for (int j = 0; j < AJ; j++) dma16(gA[j] + k, lA[j] + ab);
#pragma unroll
    for (int j = 0; j < 4; j++)  dma16(gB[j] + k, lB[j] + bb);
  };

  const int nsteps = K >> 6;
  issue(0);
  asm volatile("s_waitcnt vmcnt(0)" ::: "memory");
  __builtin_amdgcn_s_barrier();

  for (int t = 0; t < nsteps; t++) {
    if (t + 1 < nsteps) issue(t + 1);        // into buf^1 (its readers done)
    const int ab = (t & 1) * (BM * 64);
    const int bb = (t & 1) * (128 * 64);

#pragma unroll
    for (int ks2 = 0; ks2 < 2; ks2++) {      // two 32-K slices of this tile
      bf16x8 af[4], bg[NJ];
#pragma unroll
      for (int i = 0; i < 4; i++) {
        int row = wm + i * 16 + l16;
        af[i] = *(const bf16x8*)&As[ab + row * 64 + ((((ks2 << 2) + qd) ^ swz) << 3)];
      }
#pragma unroll
      for (int j = 0; j < NJ; j++) {
        int row = wn + j * 16 + l16;
        bg[j] = *(const bf16x8*)&Bs[bb + row * 64 + ((((ks2 << 2) + qd) ^ swz) << 3)];
      }
      __builtin_amdgcn_s_setprio(1);
#pragma unroll
      for (int i = 0; i < 4; i++)
#pragma unroll
        for (int j = 0; j < NJ; j++)
          acc[i][j] = __builtin_amdgcn_mfma_f32_16x16x32_bf16(af[i], bg[j], acc[i][j], 0, 0, 0);
      __builtin_amdgcn_s_setprio(0);
    }

    asm volatile("s_waitcnt lgkmcnt(0)" ::: "memory"); // my reads of buf t done
    asm volatile("s_waitcnt vmcnt(0)" ::: "memory");   // tile t+1 landed
    __builtin_amdgcn_s_barrier();                      // all waves certified
  }

#pragma unroll
  for (int i = 0; i < 4; i++)
#pragma unroll
    for (int j = 0; j < NJ; j++)
#pragma unroll
      for (int rr = 0; rr < 4; rr++) {
        long row = m0 + wm + i * 16 + qd * 4 + rr;
        int  col = n0 + wn + j * 16 + l16;
        if (C_F32)
          ((float*)Cp)[row * ldc + col + (long)blockIdx.z * sCz] = acc[i][j][rr];
        else
          ((u16*)Cp)[row * ldc + col + (long)blockIdx.z * sCz] = f2b(acc[i][j][rr]);
      }
}

// ---------------------------------------------------------------------------
// RMSNorm over rows of width W (one block / row). X,Y internal bf16; g f32.
// ---------------------------------------------------------------------------
__global__ void dsv4_rmsnorm(const u16* __restrict__ X, const float* __restrict__ g,
                             u16* __restrict__ Y, int W, float invW)
{
  __shared__ float wsum[4];
  const int row = blockIdx.x;
  const u16* x = X + (long)row * W;
  u16* y = Y + (long)row * W;
  float ss = 0.f;
  for (int i = threadIdx.x; i < W; i += 256) { float v = b2f(x[i]); ss += v * v; }
#pragma unroll
  for (int o = 32; o > 0; o >>= 1) ss += __shfl_xor(ss, o);
  const int wid = threadIdx.x >> 6;
  if ((threadIdx.x & 63) == 0) wsum[wid] = ss;
  __syncthreads();
  float tot = wsum[0] + wsum[1] + wsum[2] + wsum[3];
  float scale = rsqrtf(tot * invW + EPSF);
  for (int i = threadIdx.x; i < W; i += 256)
    y[i] = f2b(b2f(x[i]) * scale * g[i]);
}

// ---------------------------------------------------------------------------
// kv finalize: RMSNorm(128) + write V^T (128 x 2048) and RoPE'd K (2048 x 128).
// ---------------------------------------------------------------------------
__global__ void dsv4_kv_finalize(const u16* __restrict__ KVp, const float* __restrict__ g,
                                 u16* __restrict__ Kout, u16* __restrict__ VTout)
{
  const int wid  = threadIdx.x >> 6;
  const int lane = threadIdx.x & 63;
  const int row  = blockIdx.x * 4 + wid;
  const u16* x = KVp + (long)row * 128;
  float x0 = b2f(x[2 * lane]);
  float x1 = b2f(x[2 * lane + 1]);
  float ss = x0 * x0 + x1 * x1;
#pragma unroll
  for (int o = 32; o > 0; o >>= 1) ss += __shfl_xor(ss, o);
  float scale = rsqrtf(ss * (1.f / 128.f) + EPSF);
  float v0 = x0 * scale * g[2 * lane];
  float v1 = x1 * scale * g[2 * lane + 1];
  VTout[(long)(2 * lane) * 2048 + row]     = f2b(v0);
  VTout[(long)(2 * lane + 1) * 2048 + row] = f2b(v1);
  float k0 = v0, k1 = v1;
  if (lane >= 32) {
    int i = lane - 32;
    float invf = powf(10000.f, -(float)i * (1.f / 32.f));
    float sn, cc;
    sincosf((float)row * invf, &sn, &cc);               // sin FIRST, cos second
    k0 = v0 * cc - v1 * sn;
    k1 = v0 * sn + v1 * cc;
  }
  Kout[(long)row * 128 + 2 * lane]     = f2b(k0);
  Kout[(long)row * 128 + 2 * lane + 1] = f2b(k1);
}

// ---------------------------------------------------------------------------
// Flash attention v3 + VALU diet (unchanged — verified 99.7-101.4us):
//  - Defer-max (T13), lazy row-sum, one-FMA softmax scale, HW bf16 cvts,
//    s_setprio around MFMA clusters.
// ---------------------------------------------------------------------------
__device__ __forceinline__ void attn_step(
    const bf16x8* qf, bool diag, const u16* __restrict__ KsB,
    const u16* __restrict__ VsB, u16* __restrict__ PsW,
    int w, int qd, int l16, int swz, float* m, float* negm, float* l, f32x4* o)
{
  const float scl2 = 0.12754245006257017f;     // (1/sqrt(128)) * log2(e)
  const float THRU = 62.0f;                    // defer-max threshold ~ 8/scl2
  f32x4 st[4];
#pragma unroll
  for (int i = 0; i < 4; i++) { f32x4 z = {0.f, 0.f, 0.f, 0.f}; st[i] = z; }

  __builtin_amdgcn_s_setprio(1);
#pragma unroll
  for (int ks = 0; ks < 4; ks++) {             // S = Q K^T (16 x 64 per wave)
#pragma unroll
    for (int nt = 0; nt < 4; nt++) {
      int row = nt * 16 + l16;
      bf16x8 bk = *(const bf16x8*)&KsB[row * 128 + ((((ks << 2) + qd) ^ swz) << 3)];
      st[nt] = __builtin_amdgcn_mfma_f32_16x16x32_bf16(qf[ks], bk, st[nt], 0, 0, 0);
    }
  }
  __builtin_amdgcn_s_setprio(0);

  if (diag) {                                  // causal mask (raw-score domain)
#pragma unroll
    for (int nt = 0; nt < 4; nt++)
#pragma unroll
      for (int rr = 0; rr < 4; rr++)
        if ((nt * 16 + l16) > (w * 16 + qd * 4 + rr)) st[nt][rr] = -3.0e38f;
  }

  float tm[4];
  bool need = false;
#pragma unroll
  for (int rr = 0; rr < 4; rr++) {             // row max across quad's 16 lanes
    float t = fmaxf(fmaxf(st[0][rr], st[1][rr]), fmaxf(st[2][rr], st[3][rr]));
    t = fmaxf(t, __shfl_xor(t, 1));
    t = fmaxf(t, __shfl_xor(t, 2));
    t = fmaxf(t, __shfl_xor(t, 4));
    t = fmaxf(t, __shfl_xor(t, 8));
    tm[rr] = t;
    need = need || (t > m[rr] + THRU);
  }
  if (__any(need)) {                           // rare: rescale running state
#pragma unroll
    for (int rr = 0; rr < 4; rr++) {
      float mn = fmaxf(m[rr], tm[rr]);
      float a  = exp2f(scl2 * (m[rr] - mn));
      m[rr] = mn; negm[rr] = -scl2 * mn;
      l[rr] *= a;
#pragma unroll
      for (int nt = 0; nt < 8; nt++) o[nt][rr] *= a;
    }
  }

#pragma unroll
  for (int nt = 0; nt < 4; nt++)               // P + partial l + LDS (swizzled)
#pragma unroll
    for (int rr = 0; rr < 4; rr++) {
      float p = exp2f(fmaf(st[nt][rr], scl2, negm[rr]));
      l[rr] += p;
      int row = qd * 4 + rr;
      int cl2 = ((nt << 1) + (l16 >> 3)) ^ (row & 7);
      PsW[row * 64 + (cl2 << 3) + (l16 & 7)] = f2bh(p);
    }
  asm volatile("s_waitcnt lgkmcnt(0)" ::: "memory");

  __builtin_amdgcn_s_setprio(1);
#pragma unroll
  for (int ks = 0; ks < 2; ks++) {             // O += P V (16 x 128 per wave)
    bf16x8 ap = *(const bf16x8*)&PsW[l16 * 64 + ((((ks << 2) + qd) ^ swz) << 3)];
#pragma unroll
    for (int nt = 0; nt < 8; nt++) {
      int row = nt * 16 + l16;
      bf16x8 bv = *(const bf16x8*)&VsB[row * 64 + ((((ks << 2) + qd) ^ swz) << 3)];
      o[nt] = __builtin_amdgcn_mfma_f32_16x16x32_bf16(ap, bv, o[nt], 0, 0, 0);
    }
  }
  __builtin_amdgcn_s_setprio(0);
}

__global__ __launch_bounds__(256, 2)
void dsv4_attn(const u16* __restrict__ Q, const u16* __restrict__ Km,
               const u16* __restrict__ VT, const float* __restrict__ sinkp,
               u16* __restrict__ O)
{
  __shared__ __align__(16) u16 Ks[2][64 * 128];
  __shared__ __align__(16) u16 Vs[2][128 * 64];
  __shared__ __align__(16) u16 Ps[4][16 * 64];

  const int b  = blockIdx.x;                   // 0..15
  const int h  = blockIdx.y;
  const int qtA = 31 - b, qtB = b;
  const int n1 = qtA + 1, nT = n1 + qtB + 1;   // nT == 33 for all blocks
  const int tid  = threadIdx.x;
  const int lane = tid & 63;
  const int w    = tid >> 6;
  const int qd   = lane >> 4;
  const int l16  = lane & 15;
  const int swz  = l16 & 7;

  // ---- Q fragments for BOTH tiles in registers, RoPE fused ----
  bf16x8 qfA[4], qfB[4];
#pragma unroll
  for (int t = 0; t < 2; t++) {
    int srow = (t ? qtB : qtA) * 64 + w * 16 + l16;
    const u16* qp = Q + (long)srow * 4096 + h * 128 + qd * 8;
    bf16x8* qf = t ? qfB : qfA;
#pragma unroll
    for (int ks = 0; ks < 4; ks++) {
      union { int4 v; u16 hh[8]; } u;
      u.v = *(const int4*)(qp + ks * 32);
      if (ks >= 2) {                           // dh >= 64: rope pairs (in-lane)
#pragma unroll
        for (int j = 0; j < 4; j++) {
          int i = (ks - 2) * 16 + qd * 4 + j;
          float invf = exp2f((float)i * (-13.287712379549449f / 32.f));
          float sn, cc;
          sincosf((float)srow * invf, &sn, &cc);   // sin FIRST, cos second
          float x0 = b2f(u.hh[2 * j]), x1 = b2f(u.hh[2 * j + 1]);
          u.hh[2 * j]     = f2b(x0 * cc - x1 * sn);
          u.hh[2 * j + 1] = f2b(x0 * sn + x1 * cc);
        }
      }
      qf[ks] = *(bf16x8*)&u;
    }
  }

  // ---- K/V DMA source pointers (XOR-swizzled chunk) + LDS offsets ----
  const u16* gK[4]; const u16* gV[4]; int lKo[4], lVo[4];
#pragma unroll
  for (int j = 0; j < 4; j++) {
    int cl = j * 256 + tid;
    int krow = cl >> 4, kc = (cl & 15) ^ (krow & 7);
    gK[j] = Km + (long)krow * 128 + kc * 8;
    lKo[j] = (j * 256 + (tid & 192)) * 8;
    int vrow = cl >> 3, vc = (cl & 7) ^ (vrow & 7);
    gV[j] = VT + (long)vrow * 2048 + vc * 8;
    lVo[j] = (j * 256 + (tid & 192)) * 8;
  }

  float m[4], negm[4], l[4];
  f32x4 o[8];
#pragma unroll
  for (int i = 0; i < 4; i++) { m[i] = -INFINITY; negm[i] = 0.f; l[i] = 0.f; }
#pragma unroll
  for (int i = 0; i < 8; i++) { f32x4 z = {0.f, 0.f, 0.f, 0.f}; o[i] = z; }

  const float sink2 = sinkp[h] * 1.4426950408889634f;   // log2 domain

  // Preload kt=0 into buffer 0.
#pragma unroll
  for (int j = 0; j < 4; j++) { dma16(gK[j], &Ks[0][lKo[j]]); dma16(gV[j], &Vs[0][lVo[j]]); }

  for (int it = 0; it < nT; ++it) {
    int nxt = it + 1;
    if (nxt < nT) {                            // prefetch next tile's K/V
      int kt2 = (nxt < n1) ? nxt : nxt - n1;
      int pb = nxt & 1;
#pragma unroll
      for (int j = 0; j < 4; j++) {
        dma16(gK[j] + (long)kt2 * 8192, &Ks[pb][lKo[j]]);
        dma16(gV[j] + (long)kt2 * 64,   &Vs[pb][lVo[j]]);
      }
    }
    asm volatile("s_waitcnt vmcnt(8)" ::: "memory");  // current buffer landed
    asm volatile("s_barrier" ::: "memory");           // publish (no full drain)
    const int cb = it & 1;

    if (it < n1)
      attn_step(qfA, it == n1 - 1, Ks[cb], Vs[cb], Ps[w], w, qd, l16, swz, m, negm, l, o);
    else
      attn_step(qfB, it == nT - 1, Ks[cb], Vs[cb], Ps[w], w, qd, l16, swz, m, negm, l, o);

    asm volatile("s_barrier" ::: "memory");           // reads done before overwrite

    if (it == n1 - 1) {                        // finalize tile A, reset state
      float inv[4];
#pragma unroll
      for (int rr = 0; rr < 4; rr++) {
        float ls = l[rr];
        ls += __shfl_xor(ls, 1);
        ls += __shfl_xor(ls, 2);
        ls += __shfl_xor(ls, 4);
        ls += __shfl_xor(ls, 8);
        inv[rr] = 1.f / (ls + exp2f(sink2 + negm[rr]));
      }
#pragma unroll
      for (int nt = 0; nt < 8; nt++)
#pragma unroll
        for (int rr = 0; rr < 4; rr++)
          O[(long)(qtA * 64 + w * 16 + qd * 4 + rr) * 4096 + h * 128 + nt * 16 + l16] =
              f2bh(o[nt][rr] * inv[rr]);
#pragma unroll
      for (int i = 0; i < 4; i++) { m[i] = -INFINITY; negm[i] = 0.f; l[i] = 0.f; }
#pragma unroll
      for (int i = 0; i < 8; i++) { f32x4 z = {0.f, 0.f, 0.f, 0.f}; o[i] = z; }
    }
  }

  float inv[4];
#pragma unroll
  for (int rr = 0; rr < 4; rr++) {
    float ls = l[rr];
    ls += __shfl_xor(ls, 1);
    ls += __shfl_xor(ls, 2);
    ls += __shfl_xor(ls, 4);
    ls += __shfl_xor(ls, 8);
    inv[rr] = 1.f / (ls + exp2f(sink2 + negm[rr]));
  }
#pragma unroll
  for (int nt = 0; nt < 8; nt++)
#pragma unroll
    for (int rr = 0; rr < 4; rr++)
      O[(long)(qtB * 64 + w * 16 + qd * 4 + rr) * 4096 + h * 128 + nt * 16 + l16] =
          f2bh(o[nt][rr] * inv[rr]);
}

// ---------------------------------------------------------------------------
extern "C" void kernel_launch(void* const* d_in, const int* in_sizes, int n_in,
                              void* d_out, int out_size, void* d_ws, size_t ws_size,
                              hipStream_t stream)
{
  (void)in_sizes; (void)n_in; (void)out_size; (void)ws_size;
  const float* hidden = (const float*)d_in[0];
  const float* wq_a  = (const float*)d_in[2];
  const float* q_g   = (const float*)d_in[3];
  const float* wq_b  = (const float*)d_in[4];
  const float* wkv   = (const float*)d_in[5];
  const float* kv_g  = (const float*)d_in[6];
  const float* wo_a  = (const float*)d_in[7];
  const float* wo_b  = (const float*)d_in[8];
  const float* sinkp = (const float*)d_in[9];
  float* out = (float*)d_out;

  char* ws = (char*)d_ws;
  u16* hb     = (u16*)(ws);
  u16* low    = (u16*)(ws);
  u16* qab    = (u16*)(ws + (17ul << 20));
  u16* qr     = (u16*)(ws + (17ul << 20));
  u16* qbb    = (u16*)(ws + (30ul << 20));
  u16* kvb    = (u16*)(ws + (43ul << 20));
  u16* oab    = (u16*)(ws + (45ul << 20));
  u16* obb    = (u16*)(ws + (50ul << 20));
  u16* qbuf   = (u16*)(ws + (67ul << 20));
  u16* attnout= (u16*)(ws + (84ul << 20));
  u16* qr_pre = (u16*)(ws + (101ul << 20));
  u16* kvpre  = (u16*)(ws + (108ul << 20));
  u16* kmat   = (u16*)(ws + (108ul << 20) + 524288u);
  u16* vt     = (u16*)(ws + (108ul << 20) + 1048576u);

  const int BIG = 1 << 29;
  dim3 blk(256);

  dsv4_cvt<<<15616, blk, 0, stream>>>(hidden, wq_a, wq_b, wkv, wo_a, wo_b,
                                      hb, qab, qbb, kvb, oab, obb);
  // G1 (+fused wkv as col-tile 12): qr_pre = hidden@wq_a^T, kvpre = hidden@wkv^T
  dsv4_gemm<64, false><<<dim3(13, 32, 1), blk, 0, stream>>>(
      hb, 4096, 0, qab, 4096, 0, qr_pre, 1536, 0, 4096, 12, kvb, kvpre, 128);
  dsv4_rmsnorm<<<2048, blk, 0, stream>>>(qr_pre, q_g, qr, 1536, 1.f / 1536.f);
  dsv4_kv_finalize<<<512, blk, 0, stream>>>(kvpre, kv_g, kmat, vt);
  // G2: qbuf = qr @ wq_b^T  (un-roped; attn ropes Q in-register)
  dsv4_gemm<128, false><<<dim3(32, 16, 1), blk, 0, stream>>>(
      qr, 1536, 0, qbb, 1536, 0, qbuf, 4096, 0, 1536, BIG, nullptr, nullptr, 0);
  dsv4_attn<<<dim3(16, 32, 1), blk, 0, stream>>>(qbuf, kmat, vt, sinkp, attnout);
  // G4: grouped low[:, g*512:+512] = attnout[:, g*1024:+1024] @ wo_a[g]^T
  dsv4_gemm<64, false><<<dim3(4, 32, 4), blk, 0, stream>>>(
      attnout, 4096, 1024, oab, 1024, 524288, low, 2048, 512, 1024, BIG,
      nullptr, nullptr, 0);
  // G5: out = low @ wo_b^T (f32 store)
  dsv4_gemm<128, true><<<dim3(32, 16, 1), blk, 0, stream>>>(
      low, 2048, 0, obb, 2048, 0, out, 4096, 0, 2048, BIG, nullptr, nullptr, 0);
}

// Round 6
// 386.716 us; speedup vs baseline: 1.1451x; 1.0423x over previous
//
#include <hip/hip_runtime.h>

typedef unsigned short u16;
typedef __bf16 bf16x8 __attribute__((ext_vector_type(8)));
typedef float  f32x4  __attribute__((ext_vector_type(4)));

#define EPSF 1e-6f

__device__ __forceinline__ u16 f2b(float f) {
  unsigned u = __float_as_uint(f);
  u += 0x7fffu + ((u >> 16) & 1u);          // round-nearest-even
  return (u16)(u >> 16);
}
__device__ __forceinline__ float b2f(u16 u) { return __uint_as_float(((unsigned)u) << 16); }
// Native HW conversion (RNE, same bits as f2b) — lets the compiler emit v_cvt_*_bf16.
__device__ __forceinline__ u16 f2bh(float f) { return __builtin_bit_cast(u16, (__bf16)f); }

// Pack two f32 -> one dword of 2 bf16 (RNE), HW instruction.
__device__ __forceinline__ unsigned cvtpk(float lo, float hi) {
  unsigned d;
  asm("v_cvt_pk_bf16_f32 %0, %1, %2" : "=v"(d) : "v"(lo), "v"(hi));
  return d;
}

// Async global->LDS DMA, 16 B/lane. LDS dest = wave-uniform base + lane*16.
__device__ __forceinline__ void dma16(const u16* g, u16* l) {
  __builtin_amdgcn_global_load_lds(
      (const __attribute__((address_space(1))) unsigned int*)g,
      (__attribute__((address_space(3))) unsigned int*)l, 16, 0, 0);
}

// ---------------------------------------------------------------------------
// One-shot f32 -> bf16 conversion of hidden + all weights.
// ---------------------------------------------------------------------------
__global__ void dsv4_cvt(const float* __restrict__ hidden, const float* __restrict__ wq_a,
                         const float* __restrict__ wq_b, const float* __restrict__ wkv,
                         const float* __restrict__ wo_a, const float* __restrict__ wo_b,
                         u16* hb, u16* qab, u16* qbb, u16* kvb, u16* oab, u16* obb)
{
  long c = (long)blockIdx.x * 256 + threadIdx.x;
  const float* s; u16* d; long off;
  if      (c < 1048576) { s = hidden; d = hb;  off = c; }
  else if (c < 1835008) { s = wq_a;   d = qab; off = c - 1048576; }
  else if (c < 2621440) { s = wq_b;   d = qbb; off = c - 1835008; }
  else if (c < 2686976) { s = wkv;    d = kvb; off = c - 2621440; }
  else if (c < 2949120) { s = wo_a;   d = oab; off = c - 2686976; }
  else                  { s = wo_b;   d = obb; off = c - 2949120; }
  const float* p = s + off * 8;
  float4 f0 = *(const float4*)p;
  float4 f1 = *(const float4*)(p + 4);
  union { u16 h[8]; int4 v; } u;
  u.h[0] = f2b(f0.x); u.h[1] = f2b(f0.y); u.h[2] = f2b(f0.z); u.h[3] = f2b(f0.w);
  u.h[4] = f2b(f1.x); u.h[5] = f2b(f1.y); u.h[6] = f2b(f1.z); u.h[7] = f2b(f1.w);
  *(int4*)(d + off * 8) = u.v;
}

// ---------------------------------------------------------------------------
// GEMM: unchanged from round 5 (verified: BK=64, 1 barrier/tile, dbuf,
// issue-early/wait-late, setprio, 8-chunk XOR swizzle). 403us total.
// ---------------------------------------------------------------------------
template<int BM, bool C_F32>
__global__ __launch_bounds__(256, 2)
void dsv4_gemm(const u16* __restrict__ A, int lda, long sAz,
               const u16* __restrict__ B, int ldb, long sBz,
               void* __restrict__ Cv, int ldc, long sCz,
               int K, int splitTile,
               const u16* __restrict__ Baux, void* __restrict__ Caux, int ldcAux)
{
  constexpr int AJ = BM / 32;               // A dma16/thread/tile: 128->4, 64->2
  constexpr int NJ = (BM == 128) ? 4 : 2;
  __shared__ __align__(16) u16 As[2 * BM * 64];
  __shared__ __align__(16) u16 Bs[2 * 128 * 64];

  const int tid   = threadIdx.x;
  const int lane  = tid & 63;
  const int qd    = lane >> 4;
  const int l16   = lane & 15;
  const int wid   = tid >> 6;
  const int wbase = tid & 192;
  const int swz   = l16 & 7;

  int n0 = blockIdx.x * 128;
  const int m0 = blockIdx.y * BM;
  void* Cp = Cv;
  if ((int)blockIdx.x >= splitTile) {
    B = Baux; Cp = Caux; ldc = ldcAux;
    n0 = ((int)blockIdx.x - splitTile) * 128;
  }
  A += (long)blockIdx.z * sAz;
  B += (long)blockIdx.z * sBz;

  // Staging pointers: tile rows have 8 chunks of 8 u16 (16B); 8 threads/row.
  const u16* gA[AJ]; u16* lA[AJ];
#pragma unroll
  for (int j = 0; j < AJ; j++) {
    int L = j * 256 + tid, row = L >> 3, c = (L & 7) ^ (row & 7);
    gA[j] = A + (long)(m0 + row) * lda + c * 8;
    lA[j] = As + (j * 256 + wbase) * 8;
  }
  const u16* gB[4]; u16* lB[4];
#pragma unroll
  for (int j = 0; j < 4; j++) {
    int L = j * 256 + tid, row = L >> 3, c = (L & 7) ^ (row & 7);
    gB[j] = B + (long)(n0 + row) * ldb + c * 8;
    lB[j] = Bs + (j * 256 + wbase) * 8;
  }

  f32x4 acc[4][NJ];
#pragma unroll
  for (int i = 0; i < 4; i++)
#pragma unroll
    for (int j = 0; j < NJ; j++) { f32x4 z = {0.f, 0.f, 0.f, 0.f}; acc[i][j] = z; }

  const int wm = (BM == 128) ? (wid >> 1) * 64 : 0;
  const int wn = (BM == 128) ? (wid & 1) * 64 : wid * 32;

  auto issue = [&](int s) {
    const int k  = s << 6;
    const int ab = (s & 1) * (BM * 64);
    const int bb = (s & 1) * (128 * 64);
#pragma unroll
    for (int j = 0; j < AJ; j++) dma16(gA[j] + k, lA[j] + ab);
#pragma unroll
    for (int j = 0; j < 4; j++)  dma16(gB[j] + k, lB[j] + bb);
  };

  const int nsteps = K >> 6;
  issue(0);
  asm volatile("s_waitcnt vmcnt(0)" ::: "memory");
  __builtin_amdgcn_s_barrier();

  for (int t = 0; t < nsteps; t++) {
    if (t + 1 < nsteps) issue(t + 1);        // into buf^1 (its readers done)
    const int ab = (t & 1) * (BM * 64);
    const int bb = (t & 1) * (128 * 64);

#pragma unroll
    for (int ks2 = 0; ks2 < 2; ks2++) {      // two 32-K slices of this tile
      bf16x8 af[4], bg[NJ];
#pragma unroll
      for (int i = 0; i < 4; i++) {
        int row = wm + i * 16 + l16;
        af[i] = *(const bf16x8*)&As[ab + row * 64 + ((((ks2 << 2) + qd) ^ swz) << 3)];
      }
#pragma unroll
      for (int j = 0; j < NJ; j++) {
        int row = wn + j * 16 + l16;
        bg[j] = *(const bf16x8*)&Bs[bb + row * 64 + ((((ks2 << 2) + qd) ^ swz) << 3)];
      }
      __builtin_amdgcn_s_setprio(1);
#pragma unroll
      for (int i = 0; i < 4; i++)
#pragma unroll
        for (int j = 0; j < NJ; j++)
          acc[i][j] = __builtin_amdgcn_mfma_f32_16x16x32_bf16(af[i], bg[j], acc[i][j], 0, 0, 0);
      __builtin_amdgcn_s_setprio(0);
    }

    asm volatile("s_waitcnt lgkmcnt(0)" ::: "memory"); // my reads of buf t done
    asm volatile("s_waitcnt vmcnt(0)" ::: "memory");   // tile t+1 landed
    __builtin_amdgcn_s_barrier();                      // all waves certified
  }

#pragma unroll
  for (int i = 0; i < 4; i++)
#pragma unroll
    for (int j = 0; j < NJ; j++)
#pragma unroll
      for (int rr = 0; rr < 4; rr++) {
        long row = m0 + wm + i * 16 + qd * 4 + rr;
        int  col = n0 + wn + j * 16 + l16;
        if (C_F32)
          ((float*)Cp)[row * ldc + col + (long)blockIdx.z * sCz] = acc[i][j][rr];
        else
          ((u16*)Cp)[row * ldc + col + (long)blockIdx.z * sCz] = f2b(acc[i][j][rr]);
      }
}

// ---------------------------------------------------------------------------
// RMSNorm over rows of width W (one block / row). X,Y internal bf16; g f32.
// ---------------------------------------------------------------------------
__global__ void dsv4_rmsnorm(const u16* __restrict__ X, const float* __restrict__ g,
                             u16* __restrict__ Y, int W, float invW)
{
  __shared__ float wsum[4];
  const int row = blockIdx.x;
  const u16* x = X + (long)row * W;
  u16* y = Y + (long)row * W;
  float ss = 0.f;
  for (int i = threadIdx.x; i < W; i += 256) { float v = b2f(x[i]); ss += v * v; }
#pragma unroll
  for (int o = 32; o > 0; o >>= 1) ss += __shfl_xor(ss, o);
  const int wid = threadIdx.x >> 6;
  if ((threadIdx.x & 63) == 0) wsum[wid] = ss;
  __syncthreads();
  float tot = wsum[0] + wsum[1] + wsum[2] + wsum[3];
  float scale = rsqrtf(tot * invW + EPSF);
  for (int i = threadIdx.x; i < W; i += 256)
    y[i] = f2b(b2f(x[i]) * scale * g[i]);
}

// ---------------------------------------------------------------------------
// kv finalize: RMSNorm(128) + write V^T (128 x 2048) and RoPE'd K (2048 x 128).
// ---------------------------------------------------------------------------
__global__ void dsv4_kv_finalize(const u16* __restrict__ KVp, const float* __restrict__ g,
                                 u16* __restrict__ Kout, u16* __restrict__ VTout)
{
  const int wid  = threadIdx.x >> 6;
  const int lane = threadIdx.x & 63;
  const int row  = blockIdx.x * 4 + wid;
  const u16* x = KVp + (long)row * 128;
  float x0 = b2f(x[2 * lane]);
  float x1 = b2f(x[2 * lane + 1]);
  float ss = x0 * x0 + x1 * x1;
#pragma unroll
  for (int o = 32; o > 0; o >>= 1) ss += __shfl_xor(ss, o);
  float scale = rsqrtf(ss * (1.f / 128.f) + EPSF);
  float v0 = x0 * scale * g[2 * lane];
  float v1 = x1 * scale * g[2 * lane + 1];
  VTout[(long)(2 * lane) * 2048 + row]     = f2b(v0);
  VTout[(long)(2 * lane + 1) * 2048 + row] = f2b(v1);
  float k0 = v0, k1 = v1;
  if (lane >= 32) {
    int i = lane - 32;
    float invf = powf(10000.f, -(float)i * (1.f / 32.f));
    float sn, cc;
    sincosf((float)row * invf, &sn, &cc);               // sin FIRST, cos second
    k0 = v0 * cc - v1 * sn;
    k1 = v0 * sn + v1 * cc;
  }
  Kout[(long)row * 128 + 2 * lane]     = f2b(k0);
  Kout[(long)row * 128 + 2 * lane + 1] = f2b(k1);
}

// ---------------------------------------------------------------------------
// Flash attention v4: SWAPPED QK^T (T12) — S^T = mfma(K, Q).
//  - Lane (qd,l16) holds S^T[k = nt*16+qd*4+rr][q = l16]: softmax reduce is
//    in-lane tree + 2 shfls (was 16 shfls).
//  - P never touches LDS: PV A-fragment assembled in-register via
//    cvt_pk_bf16 + permlane32_swap + permlane16_swap (lane algebra verified:
//    {a1,b1}=swap32(A,B) -> {dw_j01,dw_j45}=swap16(a1,b1)).
//  - Softmax state (m, negm, l) is scalar per lane (q = l16); O-rescale /
//    finalize redistribute via 4 bpermutes (rare / once per tile).
//  - Defer-max (T13) kept; setprio kept; Ps LDS deleted (72KB -> 64KB).
// ---------------------------------------------------------------------------
__device__ __forceinline__ void attn_step(
    const bf16x8* qf, bool diag, const u16* __restrict__ KsB,
    const u16* __restrict__ VsB,
    int w, int qd, int l16, int swz, float& m, float& negm, float& l, f32x4* o)
{
  const float scl2 = 0.12754245006257017f;     // (1/sqrt(128)) * log2(e)
  const float THRU = 62.0f;                    // defer-max threshold ~ 8/scl2
  f32x4 st[4];
#pragma unroll
  for (int i = 0; i < 4; i++) { f32x4 z = {0.f, 0.f, 0.f, 0.f}; st[i] = z; }

  __builtin_amdgcn_s_setprio(1);
#pragma unroll
  for (int ks = 0; ks < 4; ks++) {             // S^T = K Q^T (64 x 16 per wave)
#pragma unroll
    for (int nt = 0; nt < 4; nt++) {
      int row = nt * 16 + l16;
      bf16x8 bk = *(const bf16x8*)&KsB[row * 128 + ((((ks << 2) + qd) ^ swz) << 3)];
      st[nt] = __builtin_amdgcn_mfma_f32_16x16x32_bf16(bk, qf[ks], st[nt], 0, 0, 0);
    }
  }
  __builtin_amdgcn_s_setprio(0);

  if (diag) {                                  // causal: mask k > q
#pragma unroll
    for (int nt = 0; nt < 4; nt++)
#pragma unroll
      for (int rr = 0; rr < 4; rr++)
        if ((nt * 16 + qd * 4 + rr) > (w * 16 + l16)) st[nt][rr] = -3.0e38f;
  }

  // row max for q=l16: in-lane tree over 16 + 2 cross-qd shfls
  float t0 = fmaxf(fmaxf(st[0][0], st[0][1]), fmaxf(st[0][2], st[0][3]));
  float t1 = fmaxf(fmaxf(st[1][0], st[1][1]), fmaxf(st[1][2], st[1][3]));
  float t2 = fmaxf(fmaxf(st[2][0], st[2][1]), fmaxf(st[2][2], st[2][3]));
  float t3 = fmaxf(fmaxf(st[3][0], st[3][1]), fmaxf(st[3][2], st[3][3]));
  float t = fmaxf(fmaxf(t0, t1), fmaxf(t2, t3));
  t = fmaxf(t, __shfl_xor(t, 16));
  t = fmaxf(t, __shfl_xor(t, 32));

  if (__any(t > m + THRU)) {                   // rare: rescale running state
    float mn = fmaxf(m, t);
    float aq = exp2f(scl2 * (m - mn));         // alpha for q = l16
    m = mn; negm = -scl2 * mn;
    l *= aq;
    float a4[4];
#pragma unroll
    for (int rr = 0; rr < 4; rr++) a4[rr] = __shfl(aq, qd * 4 + rr);  // q = qd*4+rr
#pragma unroll
    for (int nt = 0; nt < 8; nt++)
#pragma unroll
      for (int rr = 0; rr < 4; rr++) o[nt][rr] *= a4[rr];
  }

#pragma unroll
  for (int nt = 0; nt < 4; nt++)               // P = exp2(scl2*S - scl2*m), lazy l
#pragma unroll
    for (int rr = 0; rr < 4; rr++) {
      float p = exp2f(fmaf(st[nt][rr], scl2, negm));
      l += p;
      st[nt][rr] = p;
    }

  __builtin_amdgcn_s_setprio(1);
#pragma unroll
  for (int ks = 0; ks < 2; ks++) {             // O += P V (16 x 128 per wave)
    // In-register P^T -> A-fragment: lane needs P[q=l16][k=ks*32+qd*8+j].
    unsigned A0 = cvtpk(st[2 * ks][0],     st[2 * ks][1]);
    unsigned A1 = cvtpk(st[2 * ks][2],     st[2 * ks][3]);
    unsigned B0 = cvtpk(st[2 * ks + 1][0], st[2 * ks + 1][1]);
    unsigned B1 = cvtpk(st[2 * ks + 1][2], st[2 * ks + 1][3]);
    auto s0 = __builtin_amdgcn_permlane32_swap(A0, B0, false, false);
    auto u0 = __builtin_amdgcn_permlane16_swap(s0[0], s0[1], false, false);
    auto s1 = __builtin_amdgcn_permlane32_swap(A1, B1, false, false);
    auto u1 = __builtin_amdgcn_permlane16_swap(s1[0], s1[1], false, false);
    union { unsigned d[4]; bf16x8 v; } ap;
    ap.d[0] = u0[0]; ap.d[1] = u1[0]; ap.d[2] = u0[1]; ap.d[3] = u1[1];
#pragma unroll
    for (int nt = 0; nt < 8; nt++) {
      int row = nt * 16 + l16;
      bf16x8 bv = *(const bf16x8*)&VsB[row * 64 + ((((ks << 2) + qd) ^ swz) << 3)];
      o[nt] = __builtin_amdgcn_mfma_f32_16x16x32_bf16(ap.v, bv, o[nt], 0, 0, 0);
    }
  }
  __builtin_amdgcn_s_setprio(0);
}

__global__ __launch_bounds__(256, 2)
void dsv4_attn(const u16* __restrict__ Q, const u16* __restrict__ Km,
               const u16* __restrict__ VT, const float* __restrict__ sinkp,
               u16* __restrict__ O)
{
  __shared__ __align__(16) u16 Ks[2][64 * 128];
  __shared__ __align__(16) u16 Vs[2][128 * 64];

  const int b  = blockIdx.x;                   // 0..15
  const int h  = blockIdx.y;
  const int qtA = 31 - b, qtB = b;
  const int n1 = qtA + 1, nT = n1 + qtB + 1;   // nT == 33 for all blocks
  const int tid  = threadIdx.x;
  const int lane = tid & 63;
  const int w    = tid >> 6;
  const int qd   = lane >> 4;
  const int l16  = lane & 15;
  const int swz  = l16 & 7;

  // ---- Q fragments for BOTH tiles in registers, RoPE fused ----
  bf16x8 qfA[4], qfB[4];
#pragma unroll
  for (int t = 0; t < 2; t++) {
    int srow = (t ? qtB : qtA) * 64 + w * 16 + l16;
    const u16* qp = Q + (long)srow * 4096 + h * 128 + qd * 8;
    bf16x8* qf = t ? qfB : qfA;
#pragma unroll
    for (int ks = 0; ks < 4; ks++) {
      union { int4 v; u16 hh[8]; } u;
      u.v = *(const int4*)(qp + ks * 32);
      if (ks >= 2) {                           // dh >= 64: rope pairs (in-lane)
#pragma unroll
        for (int j = 0; j < 4; j++) {
          int i = (ks - 2) * 16 + qd * 4 + j;
          float invf = exp2f((float)i * (-13.287712379549449f / 32.f));
          float sn, cc;
          sincosf((float)srow * invf, &sn, &cc);   // sin FIRST, cos second
          float x0 = b2f(u.hh[2 * j]), x1 = b2f(u.hh[2 * j + 1]);
          u.hh[2 * j]     = f2b(x0 * cc - x1 * sn);
          u.hh[2 * j + 1] = f2b(x0 * sn + x1 * cc);
        }
      }
      qf[ks] = *(bf16x8*)&u;
    }
  }

  // ---- K/V DMA source pointers (XOR-swizzled chunk) + LDS offsets ----
  const u16* gK[4]; const u16* gV[4]; int lKo[4], lVo[4];
#pragma unroll
  for (int j = 0; j < 4; j++) {
    int cl = j * 256 + tid;
    int krow = cl >> 4, kc = (cl & 15) ^ (krow & 7);
    gK[j] = Km + (long)krow * 128 + kc * 8;
    lKo[j] = (j * 256 + (tid & 192)) * 8;
    int vrow = cl >> 3, vc = (cl & 7) ^ (vrow & 7);
    gV[j] = VT + (long)vrow * 2048 + vc * 8;
    lVo[j] = (j * 256 + (tid & 192)) * 8;
  }

  float m = -INFINITY, negm = 0.f, l = 0.f;
  f32x4 o[8];
#pragma unroll
  for (int i = 0; i < 8; i++) { f32x4 z = {0.f, 0.f, 0.f, 0.f}; o[i] = z; }

  const float sink2 = sinkp[h] * 1.4426950408889634f;   // log2 domain

  // Preload kt=0 into buffer 0.
#pragma unroll
  for (int j = 0; j < 4; j++) { dma16(gK[j], &Ks[0][lKo[j]]); dma16(gV[j], &Vs[0][lVo[j]]); }

  for (int it = 0; it < nT; ++it) {
    int nxt = it + 1;
    if (nxt < nT) {                            // prefetch next tile's K/V
      int kt2 = (nxt < n1) ? nxt : nxt - n1;
      int pb = nxt & 1;
#pragma unroll
      for (int j = 0; j < 4; j++) {
        dma16(gK[j] + (long)kt2 * 8192, &Ks[pb][lKo[j]]);
        dma16(gV[j] + (long)kt2 * 64,   &Vs[pb][lVo[j]]);
      }
    }
    asm volatile("s_waitcnt vmcnt(8)" ::: "memory");  // current buffer landed
    asm volatile("s_barrier" ::: "memory");           // publish (no full drain)
    const int cb = it & 1;

    if (it < n1)
      attn_step(qfA, it == n1 - 1, Ks[cb], Vs[cb], w, qd, l16, swz, m, negm, l, o);
    else
      attn_step(qfB, it == nT - 1, Ks[cb], Vs[cb], w, qd, l16, swz, m, negm, l, o);

    asm volatile("s_barrier" ::: "memory");           // reads done before overwrite

    if (it == n1 - 1) {                        // finalize tile A, reset state
      float ls = l;
      ls += __shfl_xor(ls, 16);
      ls += __shfl_xor(ls, 32);
      float inv = 1.f / (ls + exp2f(sink2 + negm));   // for q = l16
      float inv4[4];
#pragma unroll
      for (int rr = 0; rr < 4; rr++) inv4[rr] = __shfl(inv, qd * 4 + rr);
#pragma unroll
      for (int nt = 0; nt < 8; nt++)
#pragma unroll
        for (int rr = 0; rr < 4; rr++)
          O[(long)(qtA * 64 + w * 16 + qd * 4 + rr) * 4096 + h * 128 + nt * 16 + l16] =
              f2bh(o[nt][rr] * inv4[rr]);
      m = -INFINITY; negm = 0.f; l = 0.f;
#pragma unroll
      for (int i = 0; i < 8; i++) { f32x4 z = {0.f, 0.f, 0.f, 0.f}; o[i] = z; }
    }
  }

  {
    float ls = l;
    ls += __shfl_xor(ls, 16);
    ls += __shfl_xor(ls, 32);
    float inv = 1.f / (ls + exp2f(sink2 + negm));
    float inv4[4];
#pragma unroll
    for (int rr = 0; rr < 4; rr++) inv4[rr] = __shfl(inv, qd * 4 + rr);
#pragma unroll
    for (int nt = 0; nt < 8; nt++)
#pragma unroll
      for (int rr = 0; rr < 4; rr++)
        O[(long)(qtB * 64 + w * 16 + qd * 4 + rr) * 4096 + h * 128 + nt * 16 + l16] =
            f2bh(o[nt][rr] * inv4[rr]);
  }
}

// ---------------------------------------------------------------------------
extern "C" void kernel_launch(void* const* d_in, const int* in_sizes, int n_in,
                              void* d_out, int out_size, void* d_ws, size_t ws_size,
                              hipStream_t stream)
{
  (void)in_sizes; (void)n_in; (void)out_size; (void)ws_size;
  const float* hidden = (const float*)d_in[0];
  const float* wq_a  = (const float*)d_in[2];
  const float* q_g   = (const float*)d_in[3];
  const float* wq_b  = (const float*)d_in[4];
  const float* wkv   = (const float*)d_in[5];
  const float* kv_g  = (const float*)d_in[6];
  const float* wo_a  = (const float*)d_in[7];
  const float* wo_b  = (const float*)d_in[8];
  const float* sinkp = (const float*)d_in[9];
  float* out = (float*)d_out;

  char* ws = (char*)d_ws;
  u16* hb     = (u16*)(ws);
  u16* low    = (u16*)(ws);
  u16* qab    = (u16*)(ws + (17ul << 20));
  u16* qr     = (u16*)(ws + (17ul << 20));
  u16* qbb    = (u16*)(ws + (30ul << 20));
  u16* kvb    = (u16*)(ws + (43ul << 20));
  u16* oab    = (u16*)(ws + (45ul << 20));
  u16* obb    = (u16*)(ws + (50ul << 20));
  u16* qbuf   = (u16*)(ws + (67ul << 20));
  u16* attnout= (u16*)(ws + (84ul << 20));
  u16* qr_pre = (u16*)(ws + (101ul << 20));
  u16* kvpre  = (u16*)(ws + (108ul << 20));
  u16* kmat   = (u16*)(ws + (108ul << 20) + 524288u);
  u16* vt     = (u16*)(ws + (108ul << 20) + 1048576u);

  const int BIG = 1 << 29;
  dim3 blk(256);

  dsv4_cvt<<<15616, blk, 0, stream>>>(hidden, wq_a, wq_b, wkv, wo_a, wo_b,
                                      hb, qab, qbb, kvb, oab, obb);
  // G1 (+fused wkv as col-tile 12): qr_pre = hidden@wq_a^T, kvpre = hidden@wkv^T
  dsv4_gemm<64, false><<<dim3(13, 32, 1), blk, 0, stream>>>(
      hb, 4096, 0, qab, 4096, 0, qr_pre, 1536, 0, 4096, 12, kvb, kvpre, 128);
  dsv4_rmsnorm<<<2048, blk, 0, stream>>>(qr_pre, q_g, qr, 1536, 1.f / 1536.f);
  dsv4_kv_finalize<<<512, blk, 0, stream>>>(kvpre, kv_g, kmat, vt);
  // G2: qbuf = qr @ wq_b^T  (un-roped; attn ropes Q in-register)
  dsv4_gemm<128, false><<<dim3(32, 16, 1), blk, 0, stream>>>(
      qr, 1536, 0, qbb, 1536, 0, qbuf, 4096, 0, 1536, BIG, nullptr, nullptr, 0);
  dsv4_attn<<<dim3(16, 32, 1), blk, 0, stream>>>(qbuf, kmat, vt, sinkp, attnout);
  // G4: grouped low[:, g*512:+512] = attnout[:, g*1024:+1024] @ wo_a[g]^T
  dsv4_gemm<64, false><<<dim3(4, 32, 4), blk, 0, stream>>>(
      attnout, 4096, 1024, oab, 1024, 524288, low, 2048, 512, 1024, BIG,
      nullptr, nullptr, 0);
  // G5: out = low @ wo_b^T (f32 store)
  dsv4_gemm<128, true><<<dim3(32, 16, 1), blk, 0, stream>>>(
      low, 2048, 0, obb, 2048, 0, out, 4096, 0, 2048, BIG, nullptr, nullptr, 0);
}